// Round 2
// baseline (389.678 us; speedup 1.0000x reference)
//
#include <hip/hip_runtime.h>
#include <hip/hip_bf16.h>

// Swin window self-attention, fused. R7: permuted-k, shuffle-free, LDS-free.
//  - one 256-thread block per window; wave w = head w. No LDS, no barriers,
//    waves fully independent but co-located: X (25 KB) + mask (9.6 KB) are
//    L1-shared across the 4 heads, and the 4 heads write whole 512 B output
//    rows from one CU/XCD (R6 split them across 4 XCDs: FETCH 5x, WRITE 2.4x).
//  - permuted-k MFMA trick: Q.K^T and P.V are invariant under a common
//    permutation of the k axis. The projection D-layout (lane (q,l) holds
//    rows 16t+4q+r) IS the k-permuted fragment sigma(q,jj)=16(jj>>2)+4q+(jj&3),
//    identical on both operands of both products -> ALL quad-regroups
//    (160 ds_bpermute/wave in R6, the 5.2M LDS-conflict source) become
//    in-lane bf16 repacks. Zero cross-lane ops outside softmax shfl_xor.
//  - scale 1/sqrt(32) folded into Q pack; V bias folded into epilogue
//  - V projection moved after softmax to lower peak VGPR (~105)
//  - X reloaded per projection (L1-hot) to keep VGPR in budget
//  - W pre-packed to bf16 frags; bias table pre-gathered transposed (ws)

#define SEQ 49
#define CH 128
#define NH 4
#define DHD 32
#define NTAB 169

typedef __hip_bfloat16 bf16;
typedef __attribute__((ext_vector_type(8))) short bf16x8;  // 8 bf16 = 4 VGPRs
typedef __attribute__((ext_vector_type(4))) float f32x4;

#define WP_FRAGS (3*NH*2*4*64)           // 6144 frags of 8 bf16
#define WP_BYTES (WP_FRAGS*8*2)          // 98304
#define BIAS_ELEMS (NH*64*64)            // 16384
#define BIAS_BYTES (BIAS_ELEMS*4)        // 65536
#define WS_NEED ((size_t)(WP_BYTES + BIAS_BYTES))  // 163840

__device__ __forceinline__ bf16x8 pack8(float4 a, float4 b) {
    alignas(16) bf16 t[8] = {
        __float2bfloat16(a.x), __float2bfloat16(a.y),
        __float2bfloat16(a.z), __float2bfloat16(a.w),
        __float2bfloat16(b.x), __float2bfloat16(b.y),
        __float2bfloat16(b.z), __float2bfloat16(b.w)};
    return *(const bf16x8*)t;
}

__device__ __forceinline__ unsigned pk2(float lo, float hi) {
    union { bf16 h[2]; unsigned u; } r;
    r.h[0] = __float2bfloat16(lo);
    r.h[1] = __float2bfloat16(hi);
    return r.u;
}

union frag_u { unsigned u[4]; bf16x8 v; };

// Pre-pass: pack W{q,k,v} into per-head bf16 frags wp[which][h][t][ks][lane][8]
// = W[h*32 + 16t + (lane&15)][32ks + (lane>>4)*8 + jj]; and gather the
// rel-pos bias transposed: bias_t[h][n(key) 64][m(query) 64], zero-padded.
__global__ void prep_kernel(const float* __restrict__ Wq,
                            const float* __restrict__ Wk,
                            const float* __restrict__ Wv,
                            const float* __restrict__ table,
                            const int*  __restrict__ ridx,
                            bf16* __restrict__ wp,
                            float* __restrict__ bias_t) {
    int i = blockIdx.x*256 + threadIdx.x;
    if (i < WP_FRAGS) {
        int lane = i & 63, ks = (i >> 6) & 3, t = (i >> 8) & 1;
        int h = (i >> 9) & 3, which = i >> 11;
        const float* W = which == 0 ? Wq : (which == 1 ? Wk : Wv);
        const float* p = W + (h*DHD + t*16 + (lane & 15))*CH + ks*32 + (lane >> 4)*8;
        ((bf16x8*)wp)[i] = pack8(*(const float4*)p, *(const float4*)(p + 4));
    } else {
        int j = i - WP_FRAGS;
        if (j < BIAS_ELEMS) {
            int h = j >> 12, n = (j >> 6) & 63, m = j & 63;
            float v = 0.f;
            if (n < SEQ && m < SEQ) {
                int idx = ridx[m*SEQ + n];
                idx = idx < 0 ? 0 : (idx > NTAB-1 ? NTAB-1 : idx);
                v = table[idx*NH + h];
            }
            bias_t[j] = v;
        }
    }
}

template<bool WS>
__global__ __launch_bounds__(256, 4) void swin_attn_kernel(
    const float* __restrict__ hs,     // [B,49,128]
    const float* __restrict__ amask,  // [B,49,49]
    const float* __restrict__ Wq, const float* __restrict__ bq,
    const float* __restrict__ Wk, const float* __restrict__ bk,
    const float* __restrict__ Wv, const float* __restrict__ bv,
    const float* __restrict__ table,  // [169,4]
    const int*  __restrict__ ridx,    // [2401]
    const bf16*  __restrict__ wp,     // packed W frags (WS)
    const float* __restrict__ bias_t, // [4][64][64]    (WS)
    float* __restrict__ out)          // [B,49,128]
{
    const int b = blockIdx.x;
    const int h = threadIdx.x >> 6;   // wave = head
    const int lane = threadIdx.x & 63;
    const int l = lane & 15;
    const int q = lane >> 4;

    const float* xb = hs + (size_t)b*SEQ*CH;
    const f32x4 z4 = {0.f, 0.f, 0.f, 0.f};

    // X canonical B/A-frag: X[16rt + l][32ks + 8q + jj]; rows clamped to 48
    // (row>=49 garbage harmless: m-garbage never stored, n-garbage gets P=0).
    auto loadX = [&](int rt, int ks) -> bf16x8 {
        int row = rt*16 + l; row = row > SEQ-1 ? SEQ-1 : row;
        const float* p = xb + row*CH + ks*32 + q*8;
        return pack8(*(const float4*)p, *(const float4*)(p + 4));
    };
    auto loadW = [&](int which, int t, int ks) -> bf16x8 {
        if (WS) {
            return *(const bf16x8*)(wp +
                ((((size_t)(which*NH + h)*2 + t)*4 + ks)*64 + lane)*8);
        } else {
            const float* W = which == 0 ? Wq : (which == 1 ? Wk : Wv);
            const float* p = W + (h*DHD + t*16 + l)*CH + ks*32 + q*8;
            return pack8(*(const float4*)p, *(const float4*)(p + 4));
        }
    };

    // ---- Q^T / K^T projections (A=W, B=X): D lane (q,l) holds
    // acc[t][rt][r] = {Q,K}[c = 16t+4q+r][row = 16rt+l]. Packed DIRECTLY as
    // permuted-k frags (slot (q,jj) <-> channel 16(jj>>2)+4q+(jj&3)): no
    // cross-lane movement. Scale folded into Q; bias per (t,r).
    bf16x8 fQ[4], fK[4];
#pragma unroll
    for (int which = 0; which < 2; ++which) {
        f32x4 acc[2][4] = {{z4,z4,z4,z4},{z4,z4,z4,z4}};  // [c-tile][row-tile]
#pragma unroll
        for (int ks = 0; ks < 4; ++ks) {
            bf16x8 xf[4];
#pragma unroll
            for (int rt = 0; rt < 4; ++rt) xf[rt] = loadX(rt, ks);
#pragma unroll
            for (int t = 0; t < 2; ++t) {
                const bf16x8 wf = loadW(which, t, ks);
#pragma unroll
                for (int rt = 0; rt < 4; ++rt)
                    acc[t][rt] = __builtin_amdgcn_mfma_f32_16x16x32_bf16(
                        wf, xf[rt], acc[t][rt], 0, 0, 0);
            }
        }
        const float* bvec = which == 0 ? bq : bk;
        const float sc = which == 0 ? 0.17677669529663687f : 1.0f; // 1/sqrt(32)
        float bb[2][4];
#pragma unroll
        for (int t = 0; t < 2; ++t)
#pragma unroll
            for (int r = 0; r < 4; ++r)
                bb[t][r] = bvec[h*DHD + t*16 + 4*q + r];
#pragma unroll
        for (int rt = 0; rt < 4; ++rt) {
            frag_u f;
            f.u[0] = pk2((acc[0][rt][0]+bb[0][0])*sc, (acc[0][rt][1]+bb[0][1])*sc);
            f.u[1] = pk2((acc[0][rt][2]+bb[0][2])*sc, (acc[0][rt][3]+bb[0][3])*sc);
            f.u[2] = pk2((acc[1][rt][0]+bb[1][0])*sc, (acc[1][rt][1]+bb[1][1])*sc);
            f.u[3] = pk2((acc[1][rt][2]+bb[1][2])*sc, (acc[1][rt][3]+bb[1][3])*sc);
            if (which == 0) fQ[rt] = f.v; else fK[rt] = f.v;
        }
    }

    // ---- S^T = K Q^T (both operands k-permuted identically):
    // lane (q,l) holds S^T[n = 16kt+4q+r][m = 16qt+l] ----
    f32x4 S[4][4];   // [kt][qt]
    __builtin_amdgcn_s_setprio(1);
#pragma unroll
    for (int kt = 0; kt < 4; ++kt)
#pragma unroll
        for (int qt = 0; qt < 4; ++qt)
            S[kt][qt] = __builtin_amdgcn_mfma_f32_16x16x32_bf16(
                fK[kt], fQ[qt], z4, 0, 0, 0);
    __builtin_amdgcn_s_setprio(0);

    // ---- softmax over n (2 shfl_xor across quads); P stays in-lane ----
    const float* maskb = amask + (size_t)b*SEQ*SEQ;
    const float* biash = WS ? bias_t + h*4096 : nullptr;
    unsigned pkp[4][4][2];
#pragma unroll
    for (int qt = 0; qt < 4; ++qt) {
        const int m = qt*16 + l;
        const int mc = m > SEQ-1 ? SEQ-1 : m;
        const float* mrow = maskb + (size_t)mc*SEQ;
        float mx = -3.0e38f;
#pragma unroll
        for (int kt = 0; kt < 4; ++kt)
#pragma unroll
            for (int r = 0; r < 4; ++r) {
                const int n = kt*16 + 4*q + r;
                const int nc = n > SEQ-1 ? SEQ-1 : n;
                float bt;
                if (WS) {
                    bt = biash[n*64 + m];           // zero-padded, no clamp
                } else {
                    int idx = ridx[mc*SEQ + nc];
                    idx = idx < 0 ? 0 : (idx > NTAB-1 ? NTAB-1 : idx);
                    bt = table[idx*NH + h];
                }
                const float s = (n < SEQ) ? S[kt][qt][r] + bt + mrow[nc]
                                          : -30000.f;
                S[kt][qt][r] = s;
                mx = fmaxf(mx, s);
            }
        mx = fmaxf(mx, __shfl_xor(mx, 16));
        mx = fmaxf(mx, __shfl_xor(mx, 32));
        float sum = 0.f;
#pragma unroll
        for (int kt = 0; kt < 4; ++kt)
#pragma unroll
            for (int r = 0; r < 4; ++r) {
                const float e = __expf(S[kt][qt][r] - mx);
                S[kt][qt][r] = e;
                sum += e;
            }
        sum += __shfl_xor(sum, 16);
        sum += __shfl_xor(sum, 32);
        const float inv = 1.f / sum;
#pragma unroll
        for (int kt = 0; kt < 4; ++kt) {
            pkp[kt][qt][0] = pk2(S[kt][qt][0]*inv, S[kt][qt][1]*inv);
            pkp[kt][qt][1] = pk2(S[kt][qt][2]*inv, S[kt][qt][3]*inv);
        }
    }

    // ---- V projection (A=X, B=W), after softmax to lower peak VGPR.
    // D lane (q,l) = V[n = 16nt+4q+r][d = 16dt+l] -> permuted-k B-frag
    // fV[dt][ks2] slot (q,jj) = V[32ks2 + 16(jj>>2) + 4q + (jj&3)][16dt+l].
    f32x4 accV[4][2] = {{z4,z4},{z4,z4},{z4,z4},{z4,z4}};  // [n-tile][d-tile]
#pragma unroll
    for (int ks = 0; ks < 4; ++ks) {
        bf16x8 xf[4];
#pragma unroll
        for (int nt = 0; nt < 4; ++nt) xf[nt] = loadX(nt, ks);
#pragma unroll
        for (int dt = 0; dt < 2; ++dt) {
            const bf16x8 wf = loadW(2, dt, ks);
#pragma unroll
            for (int nt = 0; nt < 4; ++nt)
                accV[nt][dt] = __builtin_amdgcn_mfma_f32_16x16x32_bf16(
                    xf[nt], wf, accV[nt][dt], 0, 0, 0);
        }
    }
    bf16x8 fV[2][2];
#pragma unroll
    for (int dt = 0; dt < 2; ++dt)
#pragma unroll
        for (int ks2 = 0; ks2 < 2; ++ks2) {
            frag_u f;
            f.u[0] = pk2(accV[2*ks2][dt][0],   accV[2*ks2][dt][1]);
            f.u[1] = pk2(accV[2*ks2][dt][2],   accV[2*ks2][dt][3]);
            f.u[2] = pk2(accV[2*ks2+1][dt][0], accV[2*ks2+1][dt][1]);
            f.u[3] = pk2(accV[2*ks2+1][dt][2], accV[2*ks2+1][dt][3]);
            fV[dt][ks2] = f.v;
        }

    // ---- O = P V (both operands share the permuted n-axis) ----
    f32x4 O[4][2] = {{z4,z4},{z4,z4},{z4,z4},{z4,z4}};
    __builtin_amdgcn_s_setprio(1);
#pragma unroll
    for (int qt = 0; qt < 4; ++qt)
#pragma unroll
        for (int ks2 = 0; ks2 < 2; ++ks2) {
            frag_u a;
            a.u[0] = pkp[2*ks2][qt][0];
            a.u[1] = pkp[2*ks2][qt][1];
            a.u[2] = pkp[2*ks2+1][qt][0];
            a.u[3] = pkp[2*ks2+1][qt][1];
#pragma unroll
            for (int dt = 0; dt < 2; ++dt)
                O[qt][dt] = __builtin_amdgcn_mfma_f32_16x16x32_bf16(
                    a.v, fV[dt][ks2], O[qt][dt], 0, 0, 0);
        }
    __builtin_amdgcn_s_setprio(0);

    // epilogue: O rows m = 16qt + 4q + r, cols d = 16dt + l; V-bias here
    // (softmax rows sum to 1). 4 heads of the block cover the full 512 B row.
    const float bv0 = bv[h*DHD + l];
    const float bv1 = bv[h*DHD + 16 + l];
    float* ob = out + (size_t)b*SEQ*CH + h*DHD;
#pragma unroll
    for (int qt = 0; qt < 4; ++qt)
#pragma unroll
        for (int r = 0; r < 4; ++r) {
            const int m = qt*16 + 4*q + r;
            if (m < SEQ) {
                ob[m*CH + l]      = O[qt][0][r] + bv0;
                ob[m*CH + 16 + l] = O[qt][1][r] + bv1;
            }
        }
}

extern "C" void kernel_launch(void* const* d_in, const int* in_sizes, int n_in,
                              void* d_out, int out_size, void* d_ws, size_t ws_size,
                              hipStream_t stream) {
    (void)n_in; (void)out_size;
    const int nwin = in_sizes[0] / (SEQ * CH);
    const bool usews = (d_ws != nullptr) && (ws_size >= WS_NEED);
    if (usews) {
        bf16* wp = (bf16*)d_ws;
        float* bias_t = (float*)((char*)d_ws + WP_BYTES);
        prep_kernel<<<dim3((WP_FRAGS + BIAS_ELEMS + 255)/256), dim3(256), 0, stream>>>(
            (const float*)d_in[2], (const float*)d_in[4], (const float*)d_in[6],
            (const float*)d_in[8], (const int*)d_in[9], wp, bias_t);
        swin_attn_kernel<true><<<dim3(nwin), dim3(256), 0, stream>>>(
            (const float*)d_in[0], (const float*)d_in[1],
            (const float*)d_in[2], (const float*)d_in[3],
            (const float*)d_in[4], (const float*)d_in[5],
            (const float*)d_in[6], (const float*)d_in[7],
            (const float*)d_in[8], (const int*)d_in[9],
            wp, bias_t, (float*)d_out);
    } else {
        swin_attn_kernel<false><<<dim3(nwin), dim3(256), 0, stream>>>(
            (const float*)d_in[0], (const float*)d_in[1],
            (const float*)d_in[2], (const float*)d_in[3],
            (const float*)d_in[4], (const float*)d_in[5],
            (const float*)d_in[6], (const float*)d_in[7],
            (const float*)d_in[8], (const int*)d_in[9],
            nullptr, nullptr, (float*)d_out);
    }
}

// Round 3
// 377.172 us; speedup vs baseline: 1.0332x; 1.0332x over previous
//
#include <hip/hip_runtime.h>
#include <hip/hip_bf16.h>

// Swin window self-attention, fused. R8: X-resident + epilogue write-merge.
//  - R7 skeleton kept: one 256-thread block per window, wave = head,
//    permuted-k MFMA (zero shuffles, zero LDS arrays, bank-conflict = 0).
//  - X loaded ONCE into 16 bf16x8 register frags (64 VGPR); Q and K
//    projections consume from registers (kills 2 of 3 global-load latency
//    chains + the L2 thrash that pushed FETCH to 204 MB).
//  - projections t-split: accumulators live 16 VGPRs at a time, frag words
//    written in place -> peak VGPR ~120, still 4 waves/SIMD.
//  - V projection AFTER softmax, reloading X from L1 (hot, shared by the
//    4 heads): V accs never overlap the X-resident phase.
//  - __syncthreads() before the epilogue: heads 0/1 and 2/3 co-own 256 B
//    output sectors; synced stores merge in L2 (R5 wrote 100 MB synced,
//    R7 wrote 287 MB drifted -> partial-sector evictions).
//  - scale folded into Q pack, V-bias folded into epilogue, W pre-packed,
//    bias table pre-gathered transposed (workspace).

#define SEQ 49
#define CH 128
#define NH 4
#define DHD 32
#define NTAB 169

typedef __hip_bfloat16 bf16;
typedef __attribute__((ext_vector_type(8))) short bf16x8;  // 8 bf16 = 4 VGPRs
typedef __attribute__((ext_vector_type(4))) float f32x4;

#define WP_FRAGS (3*NH*2*4*64)           // 6144 frags of 8 bf16
#define WP_BYTES (WP_FRAGS*8*2)          // 98304
#define BIAS_ELEMS (NH*64*64)            // 16384
#define BIAS_BYTES (BIAS_ELEMS*4)        // 65536
#define WS_NEED ((size_t)(WP_BYTES + BIAS_BYTES))  // 163840

__device__ __forceinline__ bf16x8 pack8(float4 a, float4 b) {
    alignas(16) bf16 t[8] = {
        __float2bfloat16(a.x), __float2bfloat16(a.y),
        __float2bfloat16(a.z), __float2bfloat16(a.w),
        __float2bfloat16(b.x), __float2bfloat16(b.y),
        __float2bfloat16(b.z), __float2bfloat16(b.w)};
    return *(const bf16x8*)t;
}

__device__ __forceinline__ unsigned pk2(float lo, float hi) {
    union { bf16 h[2]; unsigned u; } r;
    r.h[0] = __float2bfloat16(lo);
    r.h[1] = __float2bfloat16(hi);
    return r.u;
}

union frag_u { unsigned u[4]; bf16x8 v; };

// Pre-pass: pack W{q,k,v} into per-head bf16 frags wp[which][h][t][ks][lane][8]
// = W[h*32 + 16t + (lane&15)][32ks + (lane>>4)*8 + jj]; and gather the
// rel-pos bias transposed: bias_t[h][n(key) 64][m(query) 64], zero-padded.
__global__ void prep_kernel(const float* __restrict__ Wq,
                            const float* __restrict__ Wk,
                            const float* __restrict__ Wv,
                            const float* __restrict__ table,
                            const int*  __restrict__ ridx,
                            bf16* __restrict__ wp,
                            float* __restrict__ bias_t) {
    int i = blockIdx.x*256 + threadIdx.x;
    if (i < WP_FRAGS) {
        int lane = i & 63, ks = (i >> 6) & 3, t = (i >> 8) & 1;
        int h = (i >> 9) & 3, which = i >> 11;
        const float* W = which == 0 ? Wq : (which == 1 ? Wk : Wv);
        const float* p = W + (h*DHD + t*16 + (lane & 15))*CH + ks*32 + (lane >> 4)*8;
        ((bf16x8*)wp)[i] = pack8(*(const float4*)p, *(const float4*)(p + 4));
    } else {
        int j = i - WP_FRAGS;
        if (j < BIAS_ELEMS) {
            int h = j >> 12, n = (j >> 6) & 63, m = j & 63;
            float v = 0.f;
            if (n < SEQ && m < SEQ) {
                int idx = ridx[m*SEQ + n];
                idx = idx < 0 ? 0 : (idx > NTAB-1 ? NTAB-1 : idx);
                v = table[idx*NH + h];
            }
            bias_t[j] = v;
        }
    }
}

template<bool WS>
__global__ __launch_bounds__(256, 4) void swin_attn_kernel(
    const float* __restrict__ hs,     // [B,49,128]
    const float* __restrict__ amask,  // [B,49,49]
    const float* __restrict__ Wq, const float* __restrict__ bq,
    const float* __restrict__ Wk, const float* __restrict__ bk,
    const float* __restrict__ Wv, const float* __restrict__ bv,
    const float* __restrict__ table,  // [169,4]
    const int*  __restrict__ ridx,    // [2401]
    const bf16*  __restrict__ wp,     // packed W frags (WS)
    const float* __restrict__ bias_t, // [4][64][64]    (WS)
    float* __restrict__ out)          // [B,49,128]
{
    const int b = blockIdx.x;
    const int h = threadIdx.x >> 6;   // wave = head
    const int lane = threadIdx.x & 63;
    const int l = lane & 15;
    const int q = lane >> 4;

    const float* xb = hs + (size_t)b*SEQ*CH;
    const f32x4 z4 = {0.f, 0.f, 0.f, 0.f};

    // X canonical B/A-frag: X[16rt + l][32ks + 8q + jj]; rows clamped to 48
    // (row>=49 garbage harmless: m-garbage never stored, n-garbage gets P=0).
    auto loadX = [&](int rt, int ks) -> bf16x8 {
        int row = rt*16 + l; row = row > SEQ-1 ? SEQ-1 : row;
        const float* p = xb + row*CH + ks*32 + q*8;
        return pack8(*(const float4*)p, *(const float4*)(p + 4));
    };
    auto loadW = [&](int which, int t, int ks) -> bf16x8 {
        if (WS) {
            return *(const bf16x8*)(wp +
                ((((size_t)(which*NH + h)*2 + t)*4 + ks)*64 + lane)*8);
        } else {
            const float* W = which == 0 ? Wq : (which == 1 ? Wk : Wv);
            const float* p = W + (h*DHD + t*16 + l)*CH + ks*32 + q*8;
            return pack8(*(const float4*)p, *(const float4*)(p + 4));
        }
    };

    // ---- X loaded once, resident (16 frags = 64 VGPR) ----
    bf16x8 xf[4][4];
#pragma unroll
    for (int rt = 0; rt < 4; ++rt)
#pragma unroll
        for (int ks = 0; ks < 4; ++ks)
            xf[rt][ks] = loadX(rt, ks);

    // ---- Q^T / K^T projections (A=W, B=X), t-split (acc = 16 VGPR):
    // D lane (q,l) holds {Q,K}[c = 16t+4q+r][row = 16rt+l]; packed DIRECTLY
    // as permuted-k frag words (slot (q,jj) <-> channel 16(jj>>2)+4q+(jj&3)).
    frag_u uQ[4], uK[4];
#pragma unroll
    for (int which = 0; which < 2; ++which) {
        const float* bvec = which == 0 ? bq : bk;
        const float sc = which == 0 ? 0.17677669529663687f : 1.0f; // 1/sqrt(32)
#pragma unroll
        for (int t = 0; t < 2; ++t) {
            f32x4 acc[4] = {z4, z4, z4, z4};
#pragma unroll
            for (int ks = 0; ks < 4; ++ks) {
                const bf16x8 wf = loadW(which, t, ks);
#pragma unroll
                for (int rt = 0; rt < 4; ++rt)
                    acc[rt] = __builtin_amdgcn_mfma_f32_16x16x32_bf16(
                        wf, xf[rt][ks], acc[rt], 0, 0, 0);
            }
            const float b0 = bvec[h*DHD + t*16 + 4*q + 0];
            const float b1 = bvec[h*DHD + t*16 + 4*q + 1];
            const float b2 = bvec[h*DHD + t*16 + 4*q + 2];
            const float b3 = bvec[h*DHD + t*16 + 4*q + 3];
#pragma unroll
            for (int rt = 0; rt < 4; ++rt) {
                const unsigned w0 = pk2((acc[rt][0]+b0)*sc, (acc[rt][1]+b1)*sc);
                const unsigned w1 = pk2((acc[rt][2]+b2)*sc, (acc[rt][3]+b3)*sc);
                if (which == 0) { uQ[rt].u[2*t] = w0; uQ[rt].u[2*t+1] = w1; }
                else            { uK[rt].u[2*t] = w0; uK[rt].u[2*t+1] = w1; }
            }
        }
    }
    // xf dead past this point (V reloads from L1)

    // ---- S^T = K Q^T (both operands k-permuted identically):
    // lane (q,l) holds S^T[n = 16kt+4q+r][m = 16qt+l] ----
    f32x4 S[4][4];   // [kt][qt]
    __builtin_amdgcn_s_setprio(1);
#pragma unroll
    for (int kt = 0; kt < 4; ++kt)
#pragma unroll
        for (int qt = 0; qt < 4; ++qt)
            S[kt][qt] = __builtin_amdgcn_mfma_f32_16x16x32_bf16(
                uK[kt].v, uQ[qt].v, z4, 0, 0, 0);
    __builtin_amdgcn_s_setprio(0);

    // ---- softmax over n (2 shfl_xor across quads); P stays in-lane ----
    const float* maskb = amask + (size_t)b*SEQ*SEQ;
    const float* biash = WS ? bias_t + h*4096 : nullptr;
    unsigned pkp[4][4][2];
#pragma unroll
    for (int qt = 0; qt < 4; ++qt) {
        const int m = qt*16 + l;
        const int mc = m > SEQ-1 ? SEQ-1 : m;
        const float* mrow = maskb + (size_t)mc*SEQ;
        float mx = -3.0e38f;
#pragma unroll
        for (int kt = 0; kt < 4; ++kt)
#pragma unroll
            for (int r = 0; r < 4; ++r) {
                const int n = kt*16 + 4*q + r;
                const int nc = n > SEQ-1 ? SEQ-1 : n;
                float bt;
                if (WS) {
                    bt = biash[n*64 + m];           // zero-padded, no clamp
                } else {
                    int idx = ridx[mc*SEQ + nc];
                    idx = idx < 0 ? 0 : (idx > NTAB-1 ? NTAB-1 : idx);
                    bt = table[idx*NH + h];
                }
                const float s = (n < SEQ) ? S[kt][qt][r] + bt + mrow[nc]
                                          : -30000.f;
                S[kt][qt][r] = s;
                mx = fmaxf(mx, s);
            }
        mx = fmaxf(mx, __shfl_xor(mx, 16));
        mx = fmaxf(mx, __shfl_xor(mx, 32));
        float sum = 0.f;
#pragma unroll
        for (int kt = 0; kt < 4; ++kt)
#pragma unroll
            for (int r = 0; r < 4; ++r) {
                const float e = __expf(S[kt][qt][r] - mx);
                S[kt][qt][r] = e;
                sum += e;
            }
        sum += __shfl_xor(sum, 16);
        sum += __shfl_xor(sum, 32);
        const float inv = 1.f / sum;
#pragma unroll
        for (int kt = 0; kt < 4; ++kt) {
            pkp[kt][qt][0] = pk2(S[kt][qt][0]*inv, S[kt][qt][1]*inv);
            pkp[kt][qt][1] = pk2(S[kt][qt][2]*inv, S[kt][qt][3]*inv);
        }
    }

    // ---- V projection (A=X, B=W), dt-split, X reloaded from L1 (hot).
    // D lane (q,l) = V[n = 16nt+4q+r][d = 16dt+l] -> permuted-k B-frag.
    frag_u uV[2][2];
#pragma unroll
    for (int dt = 0; dt < 2; ++dt) {
        f32x4 acc[4] = {z4, z4, z4, z4};
#pragma unroll
        for (int ks = 0; ks < 4; ++ks) {
            bf16x8 xt[4];
#pragma unroll
            for (int nt = 0; nt < 4; ++nt) xt[nt] = loadX(nt, ks);
            const bf16x8 wf = loadW(2, dt, ks);
#pragma unroll
            for (int nt = 0; nt < 4; ++nt)
                acc[nt] = __builtin_amdgcn_mfma_f32_16x16x32_bf16(
                    xt[nt], wf, acc[nt], 0, 0, 0);
        }
#pragma unroll
        for (int ks2 = 0; ks2 < 2; ++ks2) {
            uV[dt][ks2].u[0] = pk2(acc[2*ks2][0],   acc[2*ks2][1]);
            uV[dt][ks2].u[1] = pk2(acc[2*ks2][2],   acc[2*ks2][3]);
            uV[dt][ks2].u[2] = pk2(acc[2*ks2+1][0], acc[2*ks2+1][1]);
            uV[dt][ks2].u[3] = pk2(acc[2*ks2+1][2], acc[2*ks2+1][3]);
        }
    }

    // ---- O = P V (both operands share the permuted n-axis) ----
    f32x4 O[4][2] = {{z4,z4},{z4,z4},{z4,z4},{z4,z4}};
    __builtin_amdgcn_s_setprio(1);
#pragma unroll
    for (int qt = 0; qt < 4; ++qt)
#pragma unroll
        for (int ks2 = 0; ks2 < 2; ++ks2) {
            frag_u a;
            a.u[0] = pkp[2*ks2][qt][0];
            a.u[1] = pkp[2*ks2][qt][1];
            a.u[2] = pkp[2*ks2+1][qt][0];
            a.u[3] = pkp[2*ks2+1][qt][1];
#pragma unroll
            for (int dt = 0; dt < 2; ++dt)
                O[qt][dt] = __builtin_amdgcn_mfma_f32_16x16x32_bf16(
                    a.v, uV[dt][ks2].v, O[qt][dt], 0, 0, 0);
        }
    __builtin_amdgcn_s_setprio(0);

    // Re-converge the 4 waves before storing: heads 0/1 and 2/3 co-own
    // 256 B output sectors; synced stores merge in L2 (kills the 2.8x
    // write amplification seen when waves drift).
    __syncthreads();

    // epilogue: O rows m = 16qt + 4q + r, cols d = 16dt + l; V-bias here
    // (softmax rows sum to 1). 4 heads of the block cover the full 512 B row.
    const float bv0 = bv[h*DHD + l];
    const float bv1 = bv[h*DHD + 16 + l];
    float* ob = out + (size_t)b*SEQ*CH + h*DHD;
#pragma unroll
    for (int qt = 0; qt < 4; ++qt)
#pragma unroll
        for (int r = 0; r < 4; ++r) {
            const int m = qt*16 + 4*q + r;
            if (m < SEQ) {
                ob[m*CH + l]      = O[qt][0][r] + bv0;
                ob[m*CH + 16 + l] = O[qt][1][r] + bv1;
            }
        }
}

extern "C" void kernel_launch(void* const* d_in, const int* in_sizes, int n_in,
                              void* d_out, int out_size, void* d_ws, size_t ws_size,
                              hipStream_t stream) {
    (void)n_in; (void)out_size;
    const int nwin = in_sizes[0] / (SEQ * CH);
    const bool usews = (d_ws != nullptr) && (ws_size >= WS_NEED);
    if (usews) {
        bf16* wp = (bf16*)d_ws;
        float* bias_t = (float*)((char*)d_ws + WP_BYTES);
        prep_kernel<<<dim3((WP_FRAGS + BIAS_ELEMS + 255)/256), dim3(256), 0, stream>>>(
            (const float*)d_in[2], (const float*)d_in[4], (const float*)d_in[6],
            (const float*)d_in[8], (const int*)d_in[9], wp, bias_t);
        swin_attn_kernel<true><<<dim3(nwin), dim3(256), 0, stream>>>(
            (const float*)d_in[0], (const float*)d_in[1],
            (const float*)d_in[2], (const float*)d_in[3],
            (const float*)d_in[4], (const float*)d_in[5],
            (const float*)d_in[6], (const float*)d_in[7],
            (const float*)d_in[8], (const int*)d_in[9],
            wp, bias_t, (float*)d_out);
    } else {
        swin_attn_kernel<false><<<dim3(nwin), dim3(256), 0, stream>>>(
            (const float*)d_in[0], (const float*)d_in[1],
            (const float*)d_in[2], (const float*)d_in[3],
            (const float*)d_in[4], (const float*)d_in[5],
            (const float*)d_in[6], (const float*)d_in[7],
            (const float*)d_in[8], (const int*)d_in[9],
            nullptr, nullptr, (float*)d_out);
    }
}

// Round 4
// 296.436 us; speedup vs baseline: 1.3145x; 1.2724x over previous
//
#include <hip/hip_runtime.h>
#include <hip/hip_bf16.h>

// Swin window self-attention, fused. R9: latency round — prefetch everything.
//  - R7/R8 skeleton: one 256-thread block per window, wave = head, permuted-k
//    MFMA (zero shuffles outside softmax, zero LDS arrays, 0 bank conflicts).
//  - X loaded ONCE (resident, 64 VGPR); V-proj moved BEFORE QK-proj so all
//    three projections consume the resident frags — no second global X chain.
//  - mask+bias gathers vectorized to float4 (4x fewer loads; bias re-laid-out
//    [h][m][n] in prep so it vectorizes over n like the mask) and
//    SOFTWARE-PIPELINED one qt-tile ahead (R5 had this; R6-R8 dropped it and
//    paid ~60 us of exposed gather latency between QK^T and softmax).
//  - PV computed swapped (mfma(V,P) -> O^T): lane holds 4 consecutive output
//    columns -> epilogue is 8 float4 stores instead of 32 dword stores
//    (tests the 2.06x WRITE_SIZE amplification theory).
//  - __launch_bounds__(256,3): spend registers on prefetch buffers, not
//    occupancy — R5 proved 12 waves/CU is enough when latency is prefetched.

#define SEQ 49
#define CH 128
#define NH 4
#define DHD 32
#define NTAB 169

typedef __hip_bfloat16 bf16;
typedef __attribute__((ext_vector_type(8))) short bf16x8;  // 8 bf16 = 4 VGPRs
typedef __attribute__((ext_vector_type(4))) float f32x4;
typedef float f32x4a __attribute__((ext_vector_type(4), aligned(4)));  // 4B-ok

#define WP_FRAGS (3*NH*2*4*64)           // 6144 frags of 8 bf16
#define WP_BYTES (WP_FRAGS*8*2)          // 98304
#define BIAS_ELEMS (NH*64*64)            // 16384
#define BIAS_BYTES (BIAS_ELEMS*4)        // 65536
#define WS_NEED ((size_t)(WP_BYTES + BIAS_BYTES))  // 163840

__device__ __forceinline__ bf16x8 pack8(float4 a, float4 b) {
    alignas(16) bf16 t[8] = {
        __float2bfloat16(a.x), __float2bfloat16(a.y),
        __float2bfloat16(a.z), __float2bfloat16(a.w),
        __float2bfloat16(b.x), __float2bfloat16(b.y),
        __float2bfloat16(b.z), __float2bfloat16(b.w)};
    return *(const bf16x8*)t;
}

__device__ __forceinline__ unsigned pk2(float lo, float hi) {
    union { bf16 h[2]; unsigned u; } r;
    r.h[0] = __float2bfloat16(lo);
    r.h[1] = __float2bfloat16(hi);
    return r.u;
}

union frag_u { unsigned u[4]; bf16x8 v; };

// Pre-pass: pack W{q,k,v} into per-head bf16 frags wp[which][h][t][ks][lane][8]
// = W[h*32 + 16t + (lane&15)][32ks + (lane>>4)*8 + jj]; and gather the
// rel-pos bias M-MAJOR: bias_m[h][m(query) 64][n(key) 64], zero-padded, so
// the hot kernel loads it as float4 over n (same shape as the mask rows).
__global__ void prep_kernel(const float* __restrict__ Wq,
                            const float* __restrict__ Wk,
                            const float* __restrict__ Wv,
                            const float* __restrict__ table,
                            const int*  __restrict__ ridx,
                            bf16* __restrict__ wp,
                            float* __restrict__ bias_m) {
    int i = blockIdx.x*256 + threadIdx.x;
    if (i < WP_FRAGS) {
        int lane = i & 63, ks = (i >> 6) & 3, t = (i >> 8) & 1;
        int h = (i >> 9) & 3, which = i >> 11;
        const float* W = which == 0 ? Wq : (which == 1 ? Wk : Wv);
        const float* p = W + (h*DHD + t*16 + (lane & 15))*CH + ks*32 + (lane >> 4)*8;
        ((bf16x8*)wp)[i] = pack8(*(const float4*)p, *(const float4*)(p + 4));
    } else {
        int j = i - WP_FRAGS;
        if (j < BIAS_ELEMS) {
            int h = j >> 12, m = (j >> 6) & 63, n = j & 63;
            float v = 0.f;
            if (m < SEQ && n < SEQ) {
                int idx = ridx[m*SEQ + n];
                idx = idx < 0 ? 0 : (idx > NTAB-1 ? NTAB-1 : idx);
                v = table[idx*NH + h];
            }
            bias_m[j] = v;
        }
    }
}

template<bool WS>
__global__ __launch_bounds__(256, 3) void swin_attn_kernel(
    const float* __restrict__ hs,     // [B,49,128]
    const float* __restrict__ amask,  // [B,49,49]
    const float* __restrict__ Wq, const float* __restrict__ bq,
    const float* __restrict__ Wk, const float* __restrict__ bk,
    const float* __restrict__ Wv, const float* __restrict__ bv,
    const float* __restrict__ table,  // [169,4]
    const int*  __restrict__ ridx,    // [2401]
    const bf16*  __restrict__ wp,     // packed W frags (WS)
    const float* __restrict__ bias_m, // [4][64 m][64 n] (WS)
    float* __restrict__ out)          // [B,49,128]
{
    const int b = blockIdx.x;
    const int h = threadIdx.x >> 6;   // wave = head
    const int lane = threadIdx.x & 63;
    const int l = lane & 15;
    const int q = lane >> 4;

    const float* xb = hs + (size_t)b*SEQ*CH;
    const f32x4 z4 = {0.f, 0.f, 0.f, 0.f};

    auto loadW = [&](int which, int t, int ks) -> bf16x8 {
        if (WS) {
            return *(const bf16x8*)(wp +
                ((((size_t)(which*NH + h)*2 + t)*4 + ks)*64 + lane)*8);
        } else {
            const float* W = which == 0 ? Wq : (which == 1 ? Wk : Wv);
            const float* p = W + (h*DHD + t*16 + l)*CH + ks*32 + q*8;
            return pack8(*(const float4*)p, *(const float4*)(p + 4));
        }
    };

    // ---- X loaded once, resident (16 frags = 64 VGPR); rows clamped to 48
    // (row>=49 garbage harmless: m-garbage never stored, n-garbage gets P=0).
    // X frag: X[16rt + l][32ks + 8q + jj].
    bf16x8 xf[4][4];
#pragma unroll
    for (int rt = 0; rt < 4; ++rt) {
        int row = rt*16 + l; row = row > SEQ-1 ? SEQ-1 : row;
        const float* xr = xb + row*CH + q*8;
#pragma unroll
        for (int ks = 0; ks < 4; ++ks)
            xf[rt][ks] = pack8(*(const float4*)(xr + ks*32),
                               *(const float4*)(xr + ks*32 + 4));
    }

    // ---- V projection FIRST (A=X, B=W), dt-split, from resident X.
    // D lane (q,l) = V[n = 16nt+4q+r][d = 16dt+l] -> permuted-k B-frag
    // uV[dt][ks2] slot (q,jj) = V[32ks2 + 16(jj>>2) + 4q + (jj&3)][16dt+l].
    frag_u uV[2][2];
#pragma unroll
    for (int dt = 0; dt < 2; ++dt) {
        f32x4 acc[4] = {z4, z4, z4, z4};
#pragma unroll
        for (int ks = 0; ks < 4; ++ks) {
            const bf16x8 wf = loadW(2, dt, ks);
#pragma unroll
            for (int nt = 0; nt < 4; ++nt)
                acc[nt] = __builtin_amdgcn_mfma_f32_16x16x32_bf16(
                    xf[nt][ks], wf, acc[nt], 0, 0, 0);
        }
#pragma unroll
        for (int ks2 = 0; ks2 < 2; ++ks2) {
            uV[dt][ks2].u[0] = pk2(acc[2*ks2][0],   acc[2*ks2][1]);
            uV[dt][ks2].u[1] = pk2(acc[2*ks2][2],   acc[2*ks2][3]);
            uV[dt][ks2].u[2] = pk2(acc[2*ks2+1][0], acc[2*ks2+1][1]);
            uV[dt][ks2].u[3] = pk2(acc[2*ks2+1][2], acc[2*ks2+1][3]);
        }
    }

    // ---- Q^T / K^T projections (A=W, B=X), t-split:
    // D lane (q,l) holds {Q,K}[c = 16t+4q+r][row = 16rt+l]; packed DIRECTLY
    // as permuted-k frag words (slot (q,jj) <-> channel 16(jj>>2)+4q+(jj&3)).
    frag_u uQ[4], uK[4];
#pragma unroll
    for (int which = 0; which < 2; ++which) {
        const float* bvec = which == 0 ? bq : bk;
        const float sc = which == 0 ? 0.17677669529663687f : 1.0f; // 1/sqrt(32)
#pragma unroll
        for (int t = 0; t < 2; ++t) {
            f32x4 acc[4] = {z4, z4, z4, z4};
#pragma unroll
            for (int ks = 0; ks < 4; ++ks) {
                const bf16x8 wf = loadW(which, t, ks);
#pragma unroll
                for (int rt = 0; rt < 4; ++rt)
                    acc[rt] = __builtin_amdgcn_mfma_f32_16x16x32_bf16(
                        wf, xf[rt][ks], acc[rt], 0, 0, 0);
            }
            const float b0 = bvec[h*DHD + t*16 + 4*q + 0];
            const float b1 = bvec[h*DHD + t*16 + 4*q + 1];
            const float b2 = bvec[h*DHD + t*16 + 4*q + 2];
            const float b3 = bvec[h*DHD + t*16 + 4*q + 3];
#pragma unroll
            for (int rt = 0; rt < 4; ++rt) {
                const unsigned w0 = pk2((acc[rt][0]+b0)*sc, (acc[rt][1]+b1)*sc);
                const unsigned w1 = pk2((acc[rt][2]+b2)*sc, (acc[rt][3]+b3)*sc);
                if (which == 0) { uQ[rt].u[2*t] = w0; uQ[rt].u[2*t+1] = w1; }
                else            { uK[rt].u[2*t] = w0; uK[rt].u[2*t+1] = w1; }
            }
        }
    }
    // xf dead past this point

    // ---- mask+bias gather (float4 over n), software-pipelined per qt ----
    const float* maskb = amask + (size_t)b*SEQ*SEQ;
    const float* biasmh = WS ? bias_m + h*4096 : nullptr;
    auto gatherMB = [&](int qt, f32x4* pm, f32x4* pb) {
        const int m = qt*16 + l;
        const int mc = m > SEQ-1 ? SEQ-1 : m;
        const float* mr = maskb + (size_t)mc*SEQ + 4*q;
#pragma unroll
        for (int kt = 0; kt < 4; ++kt)
            pm[kt] = *(const f32x4a*)(mr + 16*kt);   // n-garbage masked later
        if (WS) {
            const float* br = biasmh + m*64 + 4*q;   // zero-padded to 64x64
#pragma unroll
            for (int kt = 0; kt < 4; ++kt)
                pb[kt] = *(const f32x4a*)(br + 16*kt);
        } else {
#pragma unroll
            for (int kt = 0; kt < 4; ++kt)
#pragma unroll
                for (int r = 0; r < 4; ++r) {
                    int n = kt*16 + 4*q + r;
                    int nc = n > SEQ-1 ? SEQ-1 : n;
                    int idx = ridx[mc*SEQ + nc];
                    idx = idx < 0 ? 0 : (idx > NTAB-1 ? NTAB-1 : idx);
                    pb[kt][r] = table[idx*NH + h];
                }
        }
    };

    f32x4 pm[2][4], pb[2][4];
    gatherMB(0, pm[0], pb[0]);        // in flight under the S-MFMAs

    // ---- S^T = K Q^T (both operands k-permuted identically):
    // lane (q,l) holds S^T[n = 16kt+4q+r][m = 16qt+l] ----
    f32x4 S[4][4];   // [kt][qt]
    __builtin_amdgcn_s_setprio(1);
#pragma unroll
    for (int kt = 0; kt < 4; ++kt)
#pragma unroll
        for (int qt = 0; qt < 4; ++qt)
            S[kt][qt] = __builtin_amdgcn_mfma_f32_16x16x32_bf16(
                uK[kt].v, uQ[qt].v, z4, 0, 0, 0);
    __builtin_amdgcn_s_setprio(0);

    // ---- softmax over n (2 shfl_xor across quads); P stays in-lane.
    // gather for qt+1 issued before consuming qt: one full softmax iteration
    // (~300 cyc) covers the load latency.
    unsigned pkp[4][4][2];
#pragma unroll
    for (int qt = 0; qt < 4; ++qt) {
        const int cur = qt & 1;
        if (qt < 3) gatherMB(qt+1, pm[cur^1], pb[cur^1]);
        float mx = -3.0e38f;
#pragma unroll
        for (int kt = 0; kt < 4; ++kt)
#pragma unroll
            for (int r = 0; r < 4; ++r) {
                const int n = kt*16 + 4*q + r;
                float s = S[kt][qt][r] + pm[cur][kt][r] + pb[cur][kt][r];
                s = (n < SEQ) ? s : -30000.f;
                S[kt][qt][r] = s;
                mx = fmaxf(mx, s);
            }
        mx = fmaxf(mx, __shfl_xor(mx, 16));
        mx = fmaxf(mx, __shfl_xor(mx, 32));
        float sum = 0.f;
#pragma unroll
        for (int kt = 0; kt < 4; ++kt)
#pragma unroll
            for (int r = 0; r < 4; ++r) {
                const float e = __expf(S[kt][qt][r] - mx);
                S[kt][qt][r] = e;
                sum += e;
            }
        sum += __shfl_xor(sum, 16);
        sum += __shfl_xor(sum, 32);
        const float inv = 1.f / sum;
#pragma unroll
        for (int kt = 0; kt < 4; ++kt) {
            pkp[kt][qt][0] = pk2(S[kt][qt][0]*inv, S[kt][qt][1]*inv);
            pkp[kt][qt][1] = pk2(S[kt][qt][2]*inv, S[kt][qt][3]*inv);
        }
    }

    // ---- O^T = V^T P^T: SWAPPED operands (mfma(uV, aP)) -> lane (q,l)
    // holds O[m = 16qt+l][d = 16dt+4q+r]: 4 CONSECUTIVE output columns ----
    f32x4 O[2][4] = {{z4,z4,z4,z4},{z4,z4,z4,z4}};   // [dt][qt]
    __builtin_amdgcn_s_setprio(1);
#pragma unroll
    for (int ks2 = 0; ks2 < 2; ++ks2)
#pragma unroll
        for (int qt = 0; qt < 4; ++qt) {
            frag_u a;
            a.u[0] = pkp[2*ks2][qt][0];
            a.u[1] = pkp[2*ks2][qt][1];
            a.u[2] = pkp[2*ks2+1][qt][0];
            a.u[3] = pkp[2*ks2+1][qt][1];
#pragma unroll
            for (int dt = 0; dt < 2; ++dt)
                O[dt][qt] = __builtin_amdgcn_mfma_f32_16x16x32_bf16(
                    uV[dt][ks2].v, a.v, O[dt][qt], 0, 0, 0);
        }
    __builtin_amdgcn_s_setprio(0);

    // Re-converge the 4 waves before storing (write-merge in L2), then
    // 8 float4 stores: lane (q,l) writes out[m=16qt+l][h*32+16dt+4q..+3].
    __syncthreads();
    const float* bvh = bv + h*DHD;
    float* ob = out + (size_t)b*SEQ*CH + h*DHD;
#pragma unroll
    for (int dt = 0; dt < 2; ++dt) {
        const f32x4 bva = *(const f32x4*)(bvh + dt*16 + 4*q);
#pragma unroll
        for (int qt = 0; qt < 4; ++qt) {
            const int m = qt*16 + l;
            if (m < SEQ)
                *(f32x4*)(ob + (size_t)m*CH + dt*16 + 4*q) = O[dt][qt] + bva;
        }
    }
}

extern "C" void kernel_launch(void* const* d_in, const int* in_sizes, int n_in,
                              void* d_out, int out_size, void* d_ws, size_t ws_size,
                              hipStream_t stream) {
    (void)n_in; (void)out_size;
    const int nwin = in_sizes[0] / (SEQ * CH);
    const bool usews = (d_ws != nullptr) && (ws_size >= WS_NEED);
    if (usews) {
        bf16* wp = (bf16*)d_ws;
        float* bias_m = (float*)((char*)d_ws + WP_BYTES);
        prep_kernel<<<dim3((WP_FRAGS + BIAS_ELEMS + 255)/256), dim3(256), 0, stream>>>(
            (const float*)d_in[2], (const float*)d_in[4], (const float*)d_in[6],
            (const float*)d_in[8], (const int*)d_in[9], wp, bias_m);
        swin_attn_kernel<true><<<dim3(nwin), dim3(256), 0, stream>>>(
            (const float*)d_in[0], (const float*)d_in[1],
            (const float*)d_in[2], (const float*)d_in[3],
            (const float*)d_in[4], (const float*)d_in[5],
            (const float*)d_in[6], (const float*)d_in[7],
            (const float*)d_in[8], (const int*)d_in[9],
            wp, bias_m, (float*)d_out);
    } else {
        swin_attn_kernel<false><<<dim3(nwin), dim3(256), 0, stream>>>(
            (const float*)d_in[0], (const float*)d_in[1],
            (const float*)d_in[2], (const float*)d_in[3],
            (const float*)d_in[4], (const float*)d_in[5],
            (const float*)d_in[6], (const float*)d_in[7],
            (const float*)d_in[8], (const int*)d_in[9],
            nullptr, nullptr, (float*)d_out);
    }
}